// Round 6
// baseline (214.436 us; speedup 1.0000x reference)
//
#include <hip/hip_runtime.h>
#include <stdint.h>

#define AS1 __attribute__((address_space(1)))
#define AS3 __attribute__((address_space(3)))

typedef float   f32x4  __attribute__((ext_vector_type(4)));
typedef __bf16  bf16x8 __attribute__((ext_vector_type(8)));
typedef uint32_t u32x4 __attribute__((ext_vector_type(4)));

// Round-half-up fp32->bf16 for a pair, packed into one dword: low16 = lo, high16 = hi.
__device__ __forceinline__ uint32_t pack_rnd(float lo, float hi) {
    uint32_t a = __float_as_uint(hi) + 0x8000u;
    uint32_t b = __float_as_uint(lo) + 0x8000u;
    return __builtin_amdgcn_perm(a, b, 0x07060302u); // bytes: a3 a2 b3 b2
}

// ---------------- Pre-kernel: weight [512][1024] fp32 -> Wt [1024][512] bf16 --------------
__global__ __launch_bounds__(256) void wt_prep(const float* __restrict__ w,
                                               uint16_t* __restrict__ wt) {
    int t = blockIdx.x * 256 + threadIdx.x;   // 131072 threads
    int n = t & 1023;
    int c = (t >> 10) << 2;                   // c-quad base, 0..508
    const float* p = w + (size_t)c * 1024 + n;
    float f0 = p[0], f1 = p[1024], f2 = p[2048], f3 = p[3072];
    uint2 r;
    r.x = pack_rnd(f0, f1);
    r.y = pack_rnd(f2, f3);
    *(uint2*)(wt + (size_t)n * 512 + c) = r;
}

// ---------------- Main kernel -------------------------------------------------------------
// v7 = v6 (X-resident, W gll-streamed) with 4x4 register blocking: wave tile 64n x 64m,
// 8 LDS reads feed 16 MFMAs (LDS:MFMA cycles ~1:1 instead of 2:1). n loop = 4 x 256n;
// W tile [256][32] = 16 KB, ring 2-deep (32 KB), prefetch distance 1 (full-step shadow,
// W is L2-hot per v4 FETCH evidence). LDS = 128 KB X + 32 KB ring = 160 KB. 64 steps.
__global__ __launch_bounds__(512, 2) void tconv_gemm(const float* __restrict__ x,
                                                     const uint16_t* __restrict__ wt,
                                                     const float* __restrict__ bias,
                                                     float* __restrict__ out) {
    extern __shared__ uint16_t lds[]; // [0,65536): X panel; [65536,81920): W ring 2x8192

    const int tid  = threadIdx.x;
    const int l    = tid & 63;
    const int wv   = tid >> 6;      // 0..7
    const int l15  = l & 15;
    const int quad = l >> 4;

    const int blk = blockIdx.x;     // 0..255
    const int b   = blk >> 5;       // batch
    const int p0  = (blk & 31) * 128;
    const float* xblk = x + (size_t)b * 512 * 4096 + p0;

    // ---- X staging constants: thread covers 4m x 8k per round, 4 rounds of 128 k ----
    const int mq4 = (tid & 31) * 4;
    const int ko  = tid >> 5;                 // 0..15 (k-octet within round)
    const float* xsrc = xblk + (size_t)(ko * 8) * 4096 + mq4;
    int xw0[4];
#pragma unroll
    for (int mm = 0; mm < 4; ++mm) {
        int m = mq4 + mm;
        xw0[mm] = (ko >> 3) * 8192 + m * 64 + (((ko & 7) ^ ((m >> 1) & 7)) << 3);
    }

    // ---- W gll constants: wave stages rows [wv*32, wv*32+32) of each [256][32] tile ----
    // two glls per wave: g=0 rows +0..15, g=1 rows +16..31; lane -> (row l>>2, chunk l&3)
    int wsrc_off[2], wdst_off[2];
#pragma unroll
    for (int g = 0; g < 2; ++g) {
        int R  = wv * 32 + g * 16 + (l >> 2);            // tile-local row 0..255
        int cs = (l & 3) ^ ((R >> 1) & 3);               // pre-swizzled source chunk
        wsrc_off[g] = R * 512 + cs * 8;                  // elements; + nb*131072 + t*32
        wdst_off[g] = wv * 1024 + g * 512;               // wave-uniform dest (tile-relative)
    }

    // ---- fragment offsets: wave = (wn = wv>>1, wm = wv&1), tile 64n x 64m ----
    const int wave_n = (wv >> 1) * 64;        // 0..192 within 256-n tile
    const int wave_m = (wv & 1) * 64;         // 0 / 64
    int aoff[4];
#pragma unroll
    for (int tn = 0; tn < 4; ++tn) {
        int n = wave_n + tn * 16 + l15;
        aoff[tn] = n * 32 + ((quad ^ ((n >> 1) & 3)) << 3);   // tile-relative
    }
    int boff[2][4];
#pragma unroll
    for (int p = 0; p < 2; ++p)
#pragma unroll
        for (int tm = 0; tm < 4; ++tm) {
            int m = wave_m + tm * 16 + l15;
            boff[p][tm] = m * 64 + (((p * 4 + quad) ^ ((m >> 1) & 7)) << 3);
        }

#define PACKW(VB, DST)                                                    \
    {                                                                     \
        _Pragma("unroll")                                                 \
        for (int mm = 0; mm < 4; ++mm) {                                  \
            u32x4 pk;                                                     \
            pk.x = pack_rnd(VB[0][mm], VB[1][mm]);                        \
            pk.y = pack_rnd(VB[2][mm], VB[3][mm]);                        \
            pk.z = pack_rnd(VB[4][mm], VB[5][mm]);                        \
            pk.w = pack_rnd(VB[6][mm], VB[7][mm]);                        \
            *(u32x4*)(lds + xw0[mm] + (DST)) = pk;                        \
        }                                                                 \
    }

    // ---- stage X panel (once) + W tile 0 gll ----
    {
        f32x4 va[8], vb[8];
#pragma unroll
        for (int r = 0; r < 8; ++r) va[r] = *(const f32x4*)(xsrc + (size_t)r * 4096);
        const float* x1 = xsrc + (size_t)128 * 4096;
#pragma unroll
        for (int r = 0; r < 8; ++r) vb[r] = *(const f32x4*)(x1 + (size_t)r * 4096);
        PACKW(va, 0)
        const float* x2 = xsrc + (size_t)256 * 4096;
#pragma unroll
        for (int r = 0; r < 8; ++r) va[r] = *(const f32x4*)(x2 + (size_t)r * 4096);
        PACKW(vb, 16384)
        const float* x3 = xsrc + (size_t)384 * 4096;
#pragma unroll
        for (int r = 0; r < 8; ++r) vb[r] = *(const f32x4*)(x3 + (size_t)r * 4096);
        // W tile (nb=0, t=0) into ring slot 0 (newest in queue; X loads get consumed by packs)
#pragma unroll
        for (int g = 0; g < 2; ++g)
            __builtin_amdgcn_global_load_lds((AS1 void*)(wt + wsrc_off[g]),
                                             (AS3 void*)(lds + 65536 + wdst_off[g]), 16, 0, 0);
        PACKW(va, 32768)
        PACKW(vb, 49152)
    }
    asm volatile("s_waitcnt vmcnt(0) lgkmcnt(0)" ::: "memory"); // X visible + W(0) landed
    __builtin_amdgcn_sched_barrier(0);
    __builtin_amdgcn_s_barrier();
    __builtin_amdgcn_sched_barrier(0);

    f32x4 acc[4][4];
#pragma unroll
    for (int tn = 0; tn < 4; ++tn)
#pragma unroll
        for (int tm = 0; tm < 4; ++tm) acc[tn][tm] = f32x4{0.f, 0.f, 0.f, 0.f};

    const int y_base = (blk & 31) * 4;
    float* outb = out + (size_t)b * 256 * 16384;
    const int obase0 = (wv >> 1) * 16 + quad;   // o within 64-o n-tile, + tn*4

    // ---- main: 4 n-tiles x 16 k32-steps; ring slot = t&1, prefetch distance 1 ----
    for (int nb = 0; nb < 4; ++nb) {
        const size_t wnb = (size_t)nb * 131072;
#pragma unroll
        for (int t = 0; t < 16; ++t) {
            // prefetch next W tile (same nb: k-step t+1; t==15: next nb, k-step 0)
            if (nb < 3 || t < 15) {
                const size_t soff = (t < 15) ? (wnb + (t + 1) * 32) : (wnb + 131072);
                const int dst = 65536 + ((t + 1) & 1) * 8192;
#pragma unroll
                for (int g = 0; g < 2; ++g)
                    __builtin_amdgcn_global_load_lds((AS1 void*)(wt + soff + wsrc_off[g]),
                                                     (AS3 void*)(lds + dst + wdst_off[g]),
                                                     16, 0, 0);
            }

            // compute: 4 A-frags + 4 B-frags -> 16 MFMAs
            {
                const int abase = 65536 + (t & 1) * 8192;
                const int bbase = (t >> 1) * 8192;
                bf16x8 af[4], bf[4];
#pragma unroll
                for (int tn = 0; tn < 4; ++tn)
                    af[tn] = *(const bf16x8*)(lds + abase + aoff[tn]);
#pragma unroll
                for (int tm = 0; tm < 4; ++tm)
                    bf[tm] = *(const bf16x8*)(lds + bbase + boff[t & 1][tm]);
#pragma unroll
                for (int tn = 0; tn < 4; ++tn)
#pragma unroll
                    for (int tm = 0; tm < 4; ++tm)
                        acc[tn][tm] = __builtin_amdgcn_mfma_f32_16x16x32_bf16(
                            af[tn], bf[tm], acc[tn][tm], 0, 0, 0);
            }

            // end of step: my gll landed (all waves' -> barrier), my ds_reads done
            if (nb < 3 || t < 15) {
                asm volatile("s_waitcnt vmcnt(0) lgkmcnt(0)" ::: "memory");
                __builtin_amdgcn_sched_barrier(0);
                __builtin_amdgcn_s_barrier();
                __builtin_amdgcn_sched_barrier(0);
            }
        }

        // ---- epilogue for this n-tile: o = nb*64 + obase0 + tn*4; regs = (i,j) 2x2 ----
#pragma unroll
        for (int tn = 0; tn < 4; ++tn) {
            int o = nb * 64 + obase0 + tn * 4;
            float bv = bias[o];
#pragma unroll
            for (int tm = 0; tm < 4; ++tm) {
                int loc = wave_m + tm * 16 + l15;
                int hl  = loc >> 6;
                int ww  = loc & 63;
                float* p = outb + ((size_t)(o * 128 + y_base + 2 * hl)) * 128 + 2 * ww;
                f32x4 a = acc[tn][tm];
                float2 t0; t0.x = a.x + bv; t0.y = a.y + bv;   // (i=0, j=0,1)
                float2 t1; t1.x = a.z + bv; t1.y = a.w + bv;   // (i=1, j=0,1)
                *(float2*)(p)       = t0;
                *(float2*)(p + 128) = t1;
                acc[tn][tm] = f32x4{0.f, 0.f, 0.f, 0.f};
            }
        }
    }
#undef PACKW
}

extern "C" void kernel_launch(void* const* d_in, const int* in_sizes, int n_in,
                              void* d_out, int out_size, void* d_ws, size_t ws_size,
                              hipStream_t stream) {
    const float* x    = (const float*)d_in[0];  // [8][512][64][64]
    const float* w    = (const float*)d_in[1];  // [512][256][2][2] = [512][1024]
    const float* bias = (const float*)d_in[2];  // [256]
    float* out        = (float*)d_out;          // [8][256][128][128]
    uint16_t* wt      = (uint16_t*)d_ws;        // [1024][512] bf16 (1 MiB)

    // 160 KB dynamic LDS (X 128 KB + W ring 32 KB); gfx950 allows 160 KB/workgroup.
    hipFuncSetAttribute((const void*)tconv_gemm,
                        hipFuncAttributeMaxDynamicSharedMemorySize, 163840);

    wt_prep<<<512, 256, 0, stream>>>(w, wt);
    tconv_gemm<<<256, 512, 163840, stream>>>(x, wt, bias, out);
}